// Round 3
// baseline (163.976 us; speedup 1.0000x reference)
//
#include <hip/hip_runtime.h>
#include <hip/hip_cooperative_groups.h>
#include <math.h>

#define IM 128

namespace cg = cooperative_groups;

typedef float f4 __attribute__((ext_vector_type(4)));

// ---------------- fused single-dispatch kernel (cooperative) ----------------
// Phase A (blocks 0..511): each block handles (b, col, col+1): 1-D column DFT
//   of img[b,:,col] via incremental rotor -> magnitude/128 -> 128x128 matvec
//   with conv_w + LeakyReLU -> E[b,o,col] in workspace.
// grid.sync()
// Phase B (all 1024 blocks): grid-stride broadcast of E over h into
//   out[b,o,h,w] (o<128) and passthrough of x[:,2] at o=128.
__global__ __launch_bounds__(256, 4) void fused_kernel(
    const float* __restrict__ x, const float* __restrict__ cw,
    float* __restrict__ E, f4* __restrict__ out4, int total4) {
  const int bid = blockIdx.x;
  const int tid = threadIdx.x;

  __shared__ float2 data_s[2][IM];
  __shared__ float  mag_s[2][IM];

  if (bid < 512) {
    const int b   = bid >> 6;                 // 512 blocks / 64 per batch
    const int sub = tid >> 7;                 // which of 2 columns
    const int i   = tid & 127;                // frequency / output channel
    const int col = ((bid & 63) << 1) | sub;

    const float* xr = x + (size_t)(b * 3 + 0) * IM * IM;
    const float* xi = x + (size_t)(b * 3 + 1) * IM * IM;
    float2 d;
    d.x = xr[i * IM + col];
    d.y = xi[i * IM + col];
    data_s[sub][i] = d;

    // rotor for e^{-j*2*pi*i*y/128}
    const float ang = (float)(2.0 * M_PI / IM) * (float)i;
    float sn, cb;
    __sincosf(ang, &sn, &cb);
    const float sb = -sn;
    __syncthreads();

    float c = 1.f, s = 0.f, ar = 0.f, ai = 0.f;
    #pragma unroll 8
    for (int y = 0; y < IM; ++y) {
      const float2 v = data_s[sub][y];
      ar = fmaf(v.x, c, fmaf(-v.y, s, ar));
      ai = fmaf(v.y, c, fmaf( v.x, s, ai));
      const float t0 = s * sb;
      const float t1 = c * sb;
      c = fmaf(c, cb, -t0);
      s = fmaf(s, cb,  t1);
    }
    mag_s[sub][i] = sqrtf(fmaf(ar, ar, ai * ai)) * (1.0f / IM);
    __syncthreads();

    const f4* cwo = (const f4*)(cw + (size_t)i * IM);
    float acc = 0.f;
    #pragma unroll 8
    for (int g = 0; g < IM / 4; ++g) {
      const f4 wv = cwo[g];
      acc = fmaf(wv.x, mag_s[sub][4 * g + 0], acc);
      acc = fmaf(wv.y, mag_s[sub][4 * g + 1], acc);
      acc = fmaf(wv.z, mag_s[sub][4 * g + 2], acc);
      acc = fmaf(wv.w, mag_s[sub][4 * g + 3], acc);
    }
    acc = acc >= 0.f ? acc : 0.2f * acc;
    E[((size_t)b * IM + i) * IM + col] = acc;
  }

  cg::this_grid().sync();   // includes device-scope fence (cross-XCD E visibility)

  const f4* E4 = (const f4*)E;
  const f4* x4 = (const f4*)x;
  const int stride = gridDim.x * 256;
  for (int idx = bid * 256 + tid; idx < total4; idx += stride) {
    const int w4   = idx & 31;
    const int h    = (idx >> 5) & 127;
    const int rest = idx >> 12;               // b*129 + o
    const int o    = rest % 129;
    const int b    = rest / 129;
    f4 v;
    if (o < 128) {
      v = E4[(size_t)(b * 128 + o) * 32 + w4];
    } else {
      v = x4[((size_t)(b * 3 + 2) * 128 + h) * 32 + w4];
    }
    __builtin_nontemporal_store(v, &out4[idx]);
  }
}

// ---------------- fallback path (2 dispatches, proven) ----------------
__global__ __launch_bounds__(IM) void dft_conv_kernel(const float* __restrict__ x,
                                                      const float* __restrict__ cw,
                                                      float* __restrict__ E) {
    const int blk = blockIdx.x;
    const int b   = blk >> 7;
    const int col = blk & 127;
    const int tid = threadIdx.x;

    __shared__ float2 data_s[IM];
    __shared__ float  mag_s[IM];

    const float* xr = x + (size_t)(b * 3 + 0) * IM * IM;
    const float* xi = x + (size_t)(b * 3 + 1) * IM * IM;
    float2 d;
    d.x = xr[tid * IM + col];
    d.y = xi[tid * IM + col];
    data_s[tid] = d;

    const float ang = (float)(2.0 * M_PI / IM) * (float)tid;
    float sn, cb;
    __sincosf(ang, &sn, &cb);
    const float sb = -sn;
    __syncthreads();

    float c = 1.f, s = 0.f, ar = 0.f, ai = 0.f;
    #pragma unroll 8
    for (int y = 0; y < IM; ++y) {
        const float2 v = data_s[y];
        ar = fmaf(v.x, c, fmaf(-v.y, s, ar));
        ai = fmaf(v.y, c, fmaf( v.x, s, ai));
        const float t0 = s * sb;
        const float t1 = c * sb;
        c = fmaf(c, cb, -t0);
        s = fmaf(s, cb,  t1);
    }
    mag_s[tid] = sqrtf(fmaf(ar, ar, ai * ai)) * (1.0f / IM);
    __syncthreads();

    const f4* cwo = (const f4*)(cw + (size_t)tid * IM);
    float acc = 0.f;
    #pragma unroll 8
    for (int g = 0; g < IM / 4; ++g) {
        const f4 wv = cwo[g];
        acc = fmaf(wv.x, mag_s[4 * g + 0], acc);
        acc = fmaf(wv.y, mag_s[4 * g + 1], acc);
        acc = fmaf(wv.z, mag_s[4 * g + 2], acc);
        acc = fmaf(wv.w, mag_s[4 * g + 3], acc);
    }
    acc = acc >= 0.f ? acc : 0.2f * acc;
    E[((size_t)b * IM + tid) * IM + col] = acc;
}

__global__ void bcast_kernel(const f4* __restrict__ E4,
                             const f4* __restrict__ x4,
                             f4* __restrict__ out4,
                             int total) {
    const int idx = blockIdx.x * blockDim.x + threadIdx.x;
    if (idx >= total) return;
    const int w4   = idx & 31;
    const int h    = (idx >> 5) & 127;
    const int rest = idx >> 12;
    const int o    = rest % 129;
    const int b    = rest / 129;
    f4 v;
    if (o < 128) {
        v = E4[(size_t)(b * 128 + o) * 32 + w4];
    } else {
        v = x4[((size_t)(b * 3 + 2) * 128 + h) * 32 + w4];
    }
    __builtin_nontemporal_store(v, &out4[idx]);
}

extern "C" void kernel_launch(void* const* d_in, const int* in_sizes, int n_in,
                              void* d_out, int out_size, void* d_ws, size_t ws_size,
                              hipStream_t stream) {
    const float* x  = (const float*)d_in[0];
    const float* cw = (const float*)d_in[2];
    float* E = (float*)d_ws;                   // 512 KB
    f4* out4 = (f4*)d_out;
    int total4 = out_size / 4;                 // 4,227,072

    void* args[] = { (void*)&x, (void*)&cw, (void*)&E, (void*)&out4, (void*)&total4 };
    hipError_t err = hipLaunchCooperativeKernel((const void*)fused_kernel,
                                                dim3(1024), dim3(256),
                                                args, 0, stream);
    if (err != hipSuccess) {
        // fallback: proven two-dispatch path
        dft_conv_kernel<<<8 * IM, IM, 0, stream>>>(x, cw, E);
        bcast_kernel<<<(total4 + 255) / 256, 256, 0, stream>>>(
            (const f4*)E, (const f4*)x, out4, total4);
    }
}

// Round 4
// 32.290 us; speedup vs baseline: 5.0783x; 5.0783x over previous
//
#include <hip/hip_runtime.h>
#include <math.h>

#define IM 128

typedef float f4 __attribute__((ext_vector_type(4)));

// K1: fused DFT + 1x1-conv + LeakyReLU. Per (b, col) block of 128 threads.
// Phase 1: thread i computes frequency-i of the 1-D column DFT of
//          img[b, :, col] via an incremental rotor, magnitude * 1/128.
// Phase 2: thread o computes E[b,o,col] = lrelu( sum_i cw[o,i]*mag[i] ).
__global__ __launch_bounds__(IM) void dft_conv_kernel(const float* __restrict__ x,
                                                      const float* __restrict__ cw,
                                                      float* __restrict__ E) {
    const int blk = blockIdx.x;       // b*128 + col
    const int b   = blk >> 7;
    const int col = blk & 127;
    const int tid = threadIdx.x;

    __shared__ float2 data_s[IM];
    __shared__ float  mag_s[IM];

    const float* xr = x + (size_t)(b * 3 + 0) * IM * IM;
    const float* xi = x + (size_t)(b * 3 + 1) * IM * IM;
    float2 d;
    d.x = xr[tid * IM + col];
    d.y = xi[tid * IM + col];
    data_s[tid] = d;

    const float ang = (float)(2.0 * M_PI / IM) * (float)tid;
    float sn, cb;
    __sincosf(ang, &sn, &cb);
    const float sb = -sn;
    __syncthreads();

    float c = 1.f, s = 0.f, ar = 0.f, ai = 0.f;
    #pragma unroll 8
    for (int y = 0; y < IM; ++y) {
        const float2 v = data_s[y];
        ar = fmaf(v.x, c, fmaf(-v.y, s, ar));
        ai = fmaf(v.y, c, fmaf( v.x, s, ai));
        const float t0 = s * sb;
        const float t1 = c * sb;
        c = fmaf(c, cb, -t0);
        s = fmaf(s, cb,  t1);
    }
    mag_s[tid] = sqrtf(fmaf(ar, ar, ai * ai)) * (1.0f / IM);
    __syncthreads();

    const f4* cwo = (const f4*)(cw + (size_t)tid * IM);
    float acc = 0.f;
    #pragma unroll 8
    for (int g = 0; g < IM / 4; ++g) {
        const f4 wv = cwo[g];
        acc = fmaf(wv.x, mag_s[4 * g + 0], acc);
        acc = fmaf(wv.y, mag_s[4 * g + 1], acc);
        acc = fmaf(wv.z, mag_s[4 * g + 2], acc);
        acc = fmaf(wv.w, mag_s[4 * g + 3], acc);
    }
    acc = acc >= 0.f ? acc : 0.2f * acc;
    E[((size_t)b * IM + tid) * IM + col] = acc;
}

// K2: broadcast. Channels 0..127 of batch b are CONTIGUOUS in out:
//   per-batch emb region = 128ch * 4096 f4 = 524288 f4 = 2048 blocks * 256 thr.
// Each thread owns one within-batch f4 offset j (pow2 math only) and loops
// over the 8 batches: 8 independent L2-hot loads + 8 nontemporal stores.
// Blocks 2048..2063 copy the passthrough channel (x[:,2] -> out ch 128).
__global__ __launch_bounds__(256) void bcast_kernel(const f4* __restrict__ E4,
                                                    const f4* __restrict__ x4,
                                                    f4* __restrict__ out4) {
    const int bid = blockIdx.x;
    const int tid = threadIdx.x;
    const int BATCH_PITCH = 129 * 4096;       // f4 per batch in out
    if (bid < 2048) {
        const int j  = bid * 256 + tid;       // [0, 524288)
        const int o  = j >> 12;               // channel
        const int w4 = j & 31;
        const int eoff = (o << 5) | w4;       // E4 within-batch offset
        #pragma unroll 8
        for (int b = 0; b < 8; ++b) {
            const f4 v = E4[b * 4096 + eoff];
            __builtin_nontemporal_store(v, &out4[(size_t)b * BATCH_PITCH + j]);
        }
    } else {
        // passthrough: 8 batches * 4096 f4 = 32768 f4 over 16 blocks * 256 thr * 8
        const int base = (bid - 2048) * 256 + tid;   // [0, 4096)
        #pragma unroll 8
        for (int k = 0; k < 8; ++k) {
            const int j2 = base + k * 4096;          // [0, 32768)
            const int b  = j2 >> 12;
            const int j  = j2 & 4095;
            const f4 v = x4[(size_t)(b * 3 + 2) * 4096 + j];
            __builtin_nontemporal_store(v, &out4[(size_t)b * BATCH_PITCH + 128 * 4096 + j]);
        }
    }
}

extern "C" void kernel_launch(void* const* d_in, const int* in_sizes, int n_in,
                              void* d_out, int out_size, void* d_ws, size_t ws_size,
                              hipStream_t stream) {
    const float* x  = (const float*)d_in[0];
    // d_in[1] = mask, unused by the reference forward
    const float* cw = (const float*)d_in[2];
    f4* out4 = (f4*)d_out;
    float* E = (float*)d_ws;                   // 8*128*128 floats = 512 KB

    dft_conv_kernel<<<8 * IM, IM, 0, stream>>>(x, cw, E);
    bcast_kernel<<<2048 + 16, 256, 0, stream>>>((const f4*)E, (const f4*)x, out4);
}

// Round 5
// 30.436 us; speedup vs baseline: 5.3876x; 1.0609x over previous
//
#include <hip/hip_runtime.h>
#include <math.h>

#define IM 128

typedef float f4 __attribute__((ext_vector_type(4)));

// K1: fused DFT + 1x1-conv + LeakyReLU. Per (b, col) block of 128 threads.
// Phase 1: thread i computes frequency-i of the 1-D column DFT of
//          img[b, :, col] via an incremental rotor, magnitude * 1/128.
// Phase 2: thread o computes E[b,o,col] = lrelu( sum_i cw[o,i]*mag[i] ).
__global__ __launch_bounds__(IM) void dft_conv_kernel(const float* __restrict__ x,
                                                      const float* __restrict__ cw,
                                                      float* __restrict__ E) {
    const int blk = blockIdx.x;       // b*128 + col
    const int b   = blk >> 7;
    const int col = blk & 127;
    const int tid = threadIdx.x;

    __shared__ float2 data_s[IM];
    __shared__ float  mag_s[IM];

    const float* xr = x + (size_t)(b * 3 + 0) * IM * IM;
    const float* xi = x + (size_t)(b * 3 + 1) * IM * IM;
    float2 d;
    d.x = xr[tid * IM + col];
    d.y = xi[tid * IM + col];
    data_s[tid] = d;

    const float ang = (float)(2.0 * M_PI / IM) * (float)tid;
    float sn, cb;
    __sincosf(ang, &sn, &cb);
    const float sb = -sn;
    __syncthreads();

    float c = 1.f, s = 0.f, ar = 0.f, ai = 0.f;
    #pragma unroll 8
    for (int y = 0; y < IM; ++y) {
        const float2 v = data_s[y];
        ar = fmaf(v.x, c, fmaf(-v.y, s, ar));
        ai = fmaf(v.y, c, fmaf( v.x, s, ai));
        const float t0 = s * sb;
        const float t1 = c * sb;
        c = fmaf(c, cb, -t0);
        s = fmaf(s, cb,  t1);
    }
    mag_s[tid] = sqrtf(fmaf(ar, ar, ai * ai)) * (1.0f / IM);
    __syncthreads();

    const f4* cwo = (const f4*)(cw + (size_t)tid * IM);
    float acc = 0.f;
    #pragma unroll 8
    for (int g = 0; g < IM / 4; ++g) {
        const f4 wv = cwo[g];
        acc = fmaf(wv.x, mag_s[4 * g + 0], acc);
        acc = fmaf(wv.y, mag_s[4 * g + 1], acc);
        acc = fmaf(wv.z, mag_s[4 * g + 2], acc);
        acc = fmaf(wv.w, mag_s[4 * g + 3], acc);
    }
    acc = acc >= 0.f ? acc : 0.2f * acc;
    E[((size_t)b * IM + tid) * IM + col] = acc;
}

// K2: fill-shaped broadcast. Blocks 0..1023: block owns one (b,o) plane
// (128h x 128w = 4096 f4 = 16 KB). Thread: w4 = tid&31, hb = tid>>5;
// ONE E4 load, then 16 dependency-free dwordx4 stores (h = hb + 8k), each
// wave instruction writing a contiguous 4 KB line. Blocks 1024..1031:
// passthrough x[:,2] -> out channel 128 for batch (bid-1024).
__global__ __launch_bounds__(256) void bcast_kernel(const f4* __restrict__ E4,
                                                    const f4* __restrict__ x4,
                                                    f4* __restrict__ out4) {
    const int bid = blockIdx.x;
    const int tid = threadIdx.x;
    if (bid < 1024) {
        const int b  = bid >> 7;
        const int o  = bid & 127;
        const int w4 = tid & 31;
        const int hb = tid >> 5;                       // 0..7
        const f4 e = E4[(size_t)(b * 128 + o) * 32 + w4];
        f4* dst = out4 + ((size_t)(b * 129 + o) * 128) * 32 + hb * 32 + w4;
        #pragma unroll 16
        for (int k = 0; k < 16; ++k) {
            dst[k * 256] = e;                          // h = hb + 8k, +4KB/step
        }
    } else {
        const int b = bid - 1024;
        const f4* src = x4 + (size_t)(b * 3 + 2) * 4096;
        f4* dst = out4 + ((size_t)(b * 129 + 128)) * 4096;
        #pragma unroll 16
        for (int k = 0; k < 16; ++k) {
            const int idx = tid + 256 * k;
            dst[idx] = src[idx];
        }
    }
}

extern "C" void kernel_launch(void* const* d_in, const int* in_sizes, int n_in,
                              void* d_out, int out_size, void* d_ws, size_t ws_size,
                              hipStream_t stream) {
    const float* x  = (const float*)d_in[0];
    // d_in[1] = mask, unused by the reference forward
    const float* cw = (const float*)d_in[2];
    f4* out4 = (f4*)d_out;
    float* E = (float*)d_ws;                   // 8*128*128 floats = 512 KB

    dft_conv_kernel<<<8 * IM, IM, 0, stream>>>(x, cw, E);
    bcast_kernel<<<1024 + 8, 256, 0, stream>>>((const f4*)E, (const f4*)x, out4);
}

// Round 6
// 28.876 us; speedup vs baseline: 5.6787x; 1.0540x over previous
//
#include <hip/hip_runtime.h>
#include <math.h>

#define IM 128

typedef float f4 __attribute__((ext_vector_type(4)));

// K1: fused DFT + 1x1-conv + LeakyReLU, radix-4 decimated.
// Blocks 0..1023: (b, col); 128 threads, thread i = frequency / out-channel.
//   u4[p][y] = sum_q x[y+32q]*(-j)^{pq}  (p = i mod 4), then
//   X[i] = sum_{y<32} u4[i&3][y] * e^{-j*2pi*i*y/128}  via 32-step rotor.
// Blocks 1024..1031: passthrough x[:,2] -> out channel 128 (independent of E,
//   overlaps the DFT compute).
__global__ __launch_bounds__(IM) void dft_conv_kernel(const float* __restrict__ x,
                                                      const float* __restrict__ cw,
                                                      float* __restrict__ E,
                                                      f4* __restrict__ out4) {
    const int blk = blockIdx.x;
    const int tid = threadIdx.x;

    if (blk >= 1024) {                       // passthrough copy, 16 KB per batch
        const int b = blk - 1024;
        const f4* src = (const f4*)x + (size_t)(b * 3 + 2) * 4096;
        f4* dst = out4 + ((size_t)(b * 129 + 128)) * 4096;
        #pragma unroll 8
        for (int k = 0; k < 32; ++k) {
            const int idx = tid + IM * k;
            dst[idx] = src[idx];
        }
        return;
    }

    const int b   = blk >> 7;
    const int col = blk & 127;

    __shared__ float2 data_s[IM];
    __shared__ float2 u4[4][33];             // +1 pad: p-groups in distinct banks
    __shared__ float  mag_s[IM];

    const float* xr = x + (size_t)(b * 3 + 0) * IM * IM;
    const float* xi = x + (size_t)(b * 3 + 1) * IM * IM;
    float2 d;
    d.x = xr[tid * IM + col];
    d.y = xi[tid * IM + col];
    data_s[tid] = d;
    __syncthreads();

    // radix-4 combine: p = tid>>5, y = tid&31
    {
        const int p = tid >> 5;
        const int y = tid & 31;
        const float2 a0 = data_s[y];
        const float2 a1 = data_s[y + 32];
        const float2 a2 = data_s[y + 64];
        const float2 a3 = data_s[y + 96];
        float2 u;
        if (p == 0) {        // 1,1,1,1
            u.x = a0.x + a1.x + a2.x + a3.x;
            u.y = a0.y + a1.y + a2.y + a3.y;
        } else if (p == 1) { // 1,-j,-1,j
            u.x = (a0.x - a2.x) + (a1.y - a3.y);
            u.y = (a0.y - a2.y) - (a1.x - a3.x);
        } else if (p == 2) { // 1,-1,1,-1
            u.x = a0.x - a1.x + a2.x - a3.x;
            u.y = a0.y - a1.y + a2.y - a3.y;
        } else {             // 1,j,-1,-j
            u.x = (a0.x - a2.x) - (a1.y - a3.y);
            u.y = (a0.y - a2.y) + (a1.x - a3.x);
        }
        u4[p][y] = u;
    }
    __syncthreads();

    // 32-step rotor DFT: twiddle e^{-j*2pi*tid*y/128}
    const float ang = (float)(2.0 * M_PI / IM) * (float)tid;
    float sn, cb;
    __sincosf(ang, &sn, &cb);
    const float sb = -sn;

    const float2* up = u4[tid & 3];
    float c = 1.f, s = 0.f, ar = 0.f, ai = 0.f;
    #pragma unroll
    for (int y = 0; y < 32; ++y) {
        const float2 v = up[y];
        ar = fmaf(v.x, c, fmaf(-v.y, s, ar));
        ai = fmaf(v.y, c, fmaf( v.x, s, ai));
        const float t0 = s * sb;
        const float t1 = c * sb;
        c = fmaf(c, cb, -t0);
        s = fmaf(s, cb,  t1);
    }
    mag_s[tid] = sqrtf(fmaf(ar, ar, ai * ai)) * (1.0f / IM);
    __syncthreads();

    // conv (1x1) + LeakyReLU: thread tid = output channel o
    const f4* cwo = (const f4*)(cw + (size_t)tid * IM);
    float acc = 0.f;
    #pragma unroll 8
    for (int g = 0; g < IM / 4; ++g) {
        const f4 wv = cwo[g];
        acc = fmaf(wv.x, mag_s[4 * g + 0], acc);
        acc = fmaf(wv.y, mag_s[4 * g + 1], acc);
        acc = fmaf(wv.z, mag_s[4 * g + 2], acc);
        acc = fmaf(wv.w, mag_s[4 * g + 3], acc);
    }
    acc = acc >= 0.f ? acc : 0.2f * acc;
    E[((size_t)b * IM + tid) * IM + col] = acc;
}

// K2: fill-shaped broadcast (proven best in R5). Block owns one (b,o) plane:
// ONE E4 load per thread, 16 dependency-free dwordx4 stores, each wave
// instruction writing a contiguous 1 KB line (4 KB per 4-wave step).
__global__ __launch_bounds__(256) void bcast_kernel(const f4* __restrict__ E4,
                                                    f4* __restrict__ out4) {
    const int bid = blockIdx.x;
    const int tid = threadIdx.x;
    const int b  = bid >> 7;
    const int o  = bid & 127;
    const int w4 = tid & 31;
    const int hb = tid >> 5;                       // 0..7
    const f4 e = E4[(size_t)(b * 128 + o) * 32 + w4];
    f4* dst = out4 + ((size_t)(b * 129 + o) * 128) * 32 + hb * 32 + w4;
    #pragma unroll 16
    for (int k = 0; k < 16; ++k) {
        dst[k * 256] = e;                          // h = hb + 8k, +4KB/step
    }
}

extern "C" void kernel_launch(void* const* d_in, const int* in_sizes, int n_in,
                              void* d_out, int out_size, void* d_ws, size_t ws_size,
                              hipStream_t stream) {
    const float* x  = (const float*)d_in[0];
    // d_in[1] = mask, unused by the reference forward
    const float* cw = (const float*)d_in[2];
    f4* out4 = (f4*)d_out;
    float* E = (float*)d_ws;                   // 8*128*128 floats = 512 KB

    dft_conv_kernel<<<1024 + 8, IM, 0, stream>>>(x, cw, E, out4);
    bcast_kernel<<<1024, 256, 0, stream>>>((const f4*)E, out4);
}

// Round 7
// 28.596 us; speedup vs baseline: 5.7343x; 1.0098x over previous
//
#include <hip/hip_runtime.h>
#include <math.h>

#define IM 128

typedef float f4 __attribute__((ext_vector_type(4)));

// K1: fused DFT + 1x1-conv + LeakyReLU, radix-4 decimated.
// Blocks 0..1023: (b, col); 128 threads, thread i = frequency / out-channel.
//   u4[p][y] = sum_q x[y+32q]*(-j)^{pq}  (p = i mod 4), then
//   X[i] = sum_{y<32} u4[i&3][y] * e^{-j*2pi*i*y/128}  via 32-step rotor.
// Blocks 1024..1031: passthrough x[:,2] -> out channel 128 (independent of E,
//   overlaps the DFT compute).
__global__ __launch_bounds__(IM) void dft_conv_kernel(const float* __restrict__ x,
                                                      const float* __restrict__ cw,
                                                      float* __restrict__ E,
                                                      f4* __restrict__ out4) {
    const int blk = blockIdx.x;
    const int tid = threadIdx.x;

    if (blk >= 1024) {                       // passthrough copy, 16 KB per batch
        const int b = blk - 1024;
        const f4* src = (const f4*)x + (size_t)(b * 3 + 2) * 4096;
        f4* dst = out4 + ((size_t)(b * 129 + 128)) * 4096;
        #pragma unroll 8
        for (int k = 0; k < 32; ++k) {
            const int idx = tid + IM * k;
            dst[idx] = src[idx];
        }
        return;
    }

    const int b   = blk >> 7;
    const int col = blk & 127;

    __shared__ float2 data_s[IM];
    __shared__ float2 u4[4][33];             // +1 pad: p-groups in distinct banks
    __shared__ float  mag_s[IM];

    const float* xr = x + (size_t)(b * 3 + 0) * IM * IM;
    const float* xi = x + (size_t)(b * 3 + 1) * IM * IM;
    float2 d;
    d.x = xr[tid * IM + col];
    d.y = xi[tid * IM + col];
    data_s[tid] = d;
    __syncthreads();

    // radix-4 combine: p = tid>>5, y = tid&31
    {
        const int p = tid >> 5;
        const int y = tid & 31;
        const float2 a0 = data_s[y];
        const float2 a1 = data_s[y + 32];
        const float2 a2 = data_s[y + 64];
        const float2 a3 = data_s[y + 96];
        float2 u;
        if (p == 0) {        // 1,1,1,1
            u.x = a0.x + a1.x + a2.x + a3.x;
            u.y = a0.y + a1.y + a2.y + a3.y;
        } else if (p == 1) { // 1,-j,-1,j
            u.x = (a0.x - a2.x) + (a1.y - a3.y);
            u.y = (a0.y - a2.y) - (a1.x - a3.x);
        } else if (p == 2) { // 1,-1,1,-1
            u.x = a0.x - a1.x + a2.x - a3.x;
            u.y = a0.y - a1.y + a2.y - a3.y;
        } else {             // 1,j,-1,-j
            u.x = (a0.x - a2.x) - (a1.y - a3.y);
            u.y = (a0.y - a2.y) + (a1.x - a3.x);
        }
        u4[p][y] = u;
    }
    __syncthreads();

    // 32-step rotor DFT: twiddle e^{-j*2pi*tid*y/128}
    const float ang = (float)(2.0 * M_PI / IM) * (float)tid;
    float sn, cb;
    __sincosf(ang, &sn, &cb);
    const float sb = -sn;

    const float2* up = u4[tid & 3];
    float c = 1.f, s = 0.f, ar = 0.f, ai = 0.f;
    #pragma unroll
    for (int y = 0; y < 32; ++y) {
        const float2 v = up[y];
        ar = fmaf(v.x, c, fmaf(-v.y, s, ar));
        ai = fmaf(v.y, c, fmaf( v.x, s, ai));
        const float t0 = s * sb;
        const float t1 = c * sb;
        c = fmaf(c, cb, -t0);
        s = fmaf(s, cb,  t1);
    }
    mag_s[tid] = sqrtf(fmaf(ar, ar, ai * ai)) * (1.0f / IM);
    __syncthreads();

    // conv (1x1) + LeakyReLU: thread tid = output channel o
    const f4* cwo = (const f4*)(cw + (size_t)tid * IM);
    float acc = 0.f;
    #pragma unroll 8
    for (int g = 0; g < IM / 4; ++g) {
        const f4 wv = cwo[g];
        acc = fmaf(wv.x, mag_s[4 * g + 0], acc);
        acc = fmaf(wv.y, mag_s[4 * g + 1], acc);
        acc = fmaf(wv.z, mag_s[4 * g + 2], acc);
        acc = fmaf(wv.w, mag_s[4 * g + 3], acc);
    }
    acc = acc >= 0.f ? acc : 0.2f * acc;
    E[((size_t)b * IM + tid) * IM + col] = acc;
}

// K2: fill-shaped broadcast, half-plane granularity for CU load balance.
// Block = (b, o, half): covers 64 h-rows of one (b,o) plane (32 KB).
// Thread: ONE 16B E-load, then 8 dependency-free dwordx4 stores; each wave
// instruction writes a contiguous 1 KB line.
__global__ __launch_bounds__(256) void bcast_kernel(const f4* __restrict__ E4,
                                                    f4* __restrict__ out4) {
    const int bid  = blockIdx.x;
    const int tid  = threadIdx.x;
    const int half = bid & 1;
    const int o    = (bid >> 1) & 127;
    const int b    = bid >> 8;
    const int w4   = tid & 31;
    const int hb   = tid >> 5;                     // 0..7
    const f4 e = E4[(size_t)(b * 128 + o) * 32 + w4];
    f4* dst = out4 + ((size_t)(b * 129 + o) * 128 + half * 64 + hb) * 32 + w4;
    #pragma unroll 8
    for (int k = 0; k < 8; ++k) {
        dst[k * 256] = e;                          // h = hb + 8k, +4KB/step
    }
}

extern "C" void kernel_launch(void* const* d_in, const int* in_sizes, int n_in,
                              void* d_out, int out_size, void* d_ws, size_t ws_size,
                              hipStream_t stream) {
    const float* x  = (const float*)d_in[0];
    // d_in[1] = mask, unused by the reference forward
    const float* cw = (const float*)d_in[2];
    f4* out4 = (f4*)d_out;
    float* E = (float*)d_ws;                   // 8*128*128 floats = 512 KB

    dft_conv_kernel<<<1024 + 8, IM, 0, stream>>>(x, cw, E, out4);
    bcast_kernel<<<2048, 256, 0, stream>>>((const f4*)E, out4);
}